// Round 3
// baseline (3558.098 us; speedup 1.0000x reference)
//
#include <hip/hip_runtime.h>

// ConvLSTM fused, MI355X (gfx950). T=16, B=4, C=32, H=W=64, HID=64.
// One launch per time step. h state in d_out slices, c state in d_ws.
//
// Geometry (round-3 fix of round-2 OOB):
//  - block = 16x8 = 128 threads; each thread: 4 cols x 2 rows x 4 gates
//    -> block covers full width 64 x TILE_H=16 rows. Grid (4, HID, B).
//  - LDS tile: CHUNK=8 channels x ROWS=18 (16+2 halo) x STRIDE=68.
//    Full-width tile => L/R halo and top/bottom OOB rows are SAME-padding
//    zeros: zero LDS once, loader is pure coalesced interior copy.
//  - per input channel: 8 ds_read_b128 (aligned, 2-way bank alias = free)
//    vs 288 FMA; weights are block-uniform -> s_load + v_fmac.

#define HID    64
#define BATCH  4
#define CX     32
#define TSTEPS 16
#define HW     64
#define CHUNK  8      // input channels staged per LDS pass
#define TILE_H 16
#define ROWS   (TILE_H + 2)   // 18
#define STRIDE 68     // 64 interior + 2 halo + pad; %4==0 for b128 alignment

__device__ __forceinline__ float sigmoidf_(float x) {
    return 1.0f / (1.0f + __expf(-x));
}
__device__ __forceinline__ float tanhf_(float x) {
    return 1.0f - 2.0f / (__expf(2.0f * x) + 1.0f);
}

__device__ __forceinline__ void do_chunk(
    float tile[CHUNK][ROWS][STRIDE],
    const float* __restrict__ src,   // base of channel chunk: [CHUNK,64,64]
    const float* __restrict__ wp0, const float* __restrict__ wp1,
    const float* __restrict__ wp2, const float* __restrict__ wp3,
    int gy0, int txg, int ty, int tid, float (&acc)[4][2][4])
{
    __syncthreads();   // previous compute done (also covers initial zero-init)

    // ---- stage CHUNK channels, interior only (halo stays zero) ----
    // slots: CHUNK*ROWS*32 float2 = 4608; 128 threads -> 36 uniform iters
    for (int s = tid; s < CHUNK * ROWS * 32; s += 128) {
        int c2    = s & 31;        // float2 column (global cols 2*c2, 2*c2+1)
        int rowid = s >> 5;        // 0 .. CHUNK*ROWS-1
        int ic    = rowid / ROWS;  // magic-mul
        int r     = rowid - ic * ROWS;
        int gy    = gy0 - 1 + r;
        if ((unsigned)gy < (unsigned)HW) {
            float2 v = *(const float2*)&src[(ic << 12) + (gy << 6) + (c2 << 1)];
            *(float2*)&tile[ic][r][2 + (c2 << 1)] = v;
        }
    }
    __syncthreads();

    // ---- accumulate ----
    for (int ic = 0; ic < CHUNK; ++ic) {
        float w0[9], w1[9], w2[9], w3[9];   // block-uniform -> s_load
#pragma unroll
        for (int k = 0; k < 9; ++k) {
            w0[k] = wp0[ic * 9 + k];
            w1[k] = wp1[ic * 9 + k];
            w2[k] = wp2[ic * 9 + k];
            w3[k] = wp3[ic * 9 + k];
        }
        // LDS rows needed: 2*ty + (j+dy), j+dy in [0,3] -> rr = 0..3
        float rv[4][8];
#pragma unroll
        for (int rr = 0; rr < 4; ++rr) {
            const float* p = &tile[ic][2 * ty + rr][4 * txg];
            float4 a  = *(const float4*)p;        // lds cols 4txg .. 4txg+3
            float4 bb = *(const float4*)(p + 4);  // lds cols 4txg+4 .. 4txg+7
            rv[rr][0] = a.x;  rv[rr][1] = a.y;  rv[rr][2] = a.z;  rv[rr][3] = a.w;
            rv[rr][4] = bb.x; rv[rr][5] = bb.y; rv[rr][6] = bb.z; rv[rr][7] = bb.w;
        }
#pragma unroll
        for (int j = 0; j < 2; ++j) {
#pragma unroll
            for (int dy = 0; dy < 3; ++dy) {
#pragma unroll
                for (int q = 0; q < 4; ++q) {
#pragma unroll
                    for (int dx = 0; dx < 3; ++dx) {
                        // out col 4txg+q; tap lds col = 4txg + (q+dx+1)
                        float v = rv[j + dy][q + dx + 1];
                        int k = dy * 3 + dx;
                        acc[0][j][q] = fmaf(v, w0[k], acc[0][j][q]);
                        acc[1][j][q] = fmaf(v, w1[k], acc[1][j][q]);
                        acc[2][j][q] = fmaf(v, w2[k], acc[2][j][q]);
                        acc[3][j][q] = fmaf(v, w3[k], acc[3][j][q]);
                    }
                }
            }
        }
    }
}

__global__ __launch_bounds__(128) void convlstm_step(
    const float* __restrict__ x_t,     // [B, CX, 64, 64]
    const float* __restrict__ h_prev,  // [B, HID, 64, 64] (ignored iff first)
    const float* __restrict__ w_x2h,   // [4*HID, CX, 3, 3]
    const float* __restrict__ b_x2h,   // [4*HID]
    const float* __restrict__ w_h2h,   // [4*HID, HID, 3, 3]
    const float* __restrict__ b_h2h,   // [4*HID]
    float* __restrict__ c_state,       // [B, HID, 64, 64] in d_ws
    float* __restrict__ h_out,         // [B, HID, 64, 64] = d_out slice t
    int first)
{
    __shared__ float tile[CHUNK][ROWS][STRIDE];   // 8*18*68*4 = 38.25 KB

    const int txg = threadIdx.x;    // 0..15 (column group of 4)
    const int ty  = threadIdx.y;    // 0..7  (row pair: rows 2ty, 2ty+1)
    const int tid = ty * 16 + txg;
    const int by = blockIdx.x;      // 0..3
    const int hc = blockIdx.y;      // 0..63
    const int b  = blockIdx.z;      // 0..3
    const int gy0 = by * TILE_H;

    // zero whole tile once (halo cells are never written by the loader)
    {
        float2* p = (float2*)&tile[0][0][0];
        for (int i = tid; i < CHUNK * ROWS * STRIDE / 2; i += 128)
            p[i] = make_float2(0.f, 0.f);
    }
    // first __syncthreads inside do_chunk covers zero-init vs loader race

    float acc[4][2][4];
#pragma unroll
    for (int g = 0; g < 4; ++g)
#pragma unroll
        for (int j = 0; j < 2; ++j)
#pragma unroll
            for (int q = 0; q < 4; ++q) acc[g][j][q] = 0.f;

    // ---- x2h ----
    {
        const float* wx0 = w_x2h + (size_t)(0 * HID + hc) * CX * 9;
        const float* wx1 = w_x2h + (size_t)(1 * HID + hc) * CX * 9;
        const float* wx2 = w_x2h + (size_t)(2 * HID + hc) * CX * 9;
        const float* wx3 = w_x2h + (size_t)(3 * HID + hc) * CX * 9;
        for (int c0 = 0; c0 < CX; c0 += CHUNK) {
            do_chunk(tile, x_t + ((size_t)(b * CX + c0) << 12),
                     wx0 + c0 * 9, wx1 + c0 * 9, wx2 + c0 * 9, wx3 + c0 * 9,
                     gy0, txg, ty, tid, acc);
        }
    }

    // ---- h2h ----
    if (!first) {
        const float* wh0 = w_h2h + (size_t)(0 * HID + hc) * HID * 9;
        const float* wh1 = w_h2h + (size_t)(1 * HID + hc) * HID * 9;
        const float* wh2 = w_h2h + (size_t)(2 * HID + hc) * HID * 9;
        const float* wh3 = w_h2h + (size_t)(3 * HID + hc) * HID * 9;
        for (int c0 = 0; c0 < HID; c0 += CHUNK) {
            do_chunk(tile, h_prev + ((size_t)(b * HID + c0) << 12),
                     wh0 + c0 * 9, wh1 + c0 * 9, wh2 + c0 * 9, wh3 + c0 * 9,
                     gy0, txg, ty, tid, acc);
        }
    }

    // ---- LSTM cell update (gate order i, f, g, o) ----
    const float bi = b_x2h[0 * HID + hc] + b_h2h[0 * HID + hc];
    const float bf = b_x2h[1 * HID + hc] + b_h2h[1 * HID + hc];
    const float bg = b_x2h[2 * HID + hc] + b_h2h[2 * HID + hc];
    const float bo = b_x2h[3 * HID + hc] + b_h2h[3 * HID + hc];

#pragma unroll
    for (int j = 0; j < 2; ++j) {
        const int row = gy0 + 2 * ty + j;                  // <= 63
        const int off = ((b * HID + hc) * HW + row) * HW + 4 * txg;
        float4 cp = make_float4(0.f, 0.f, 0.f, 0.f);
        if (!first) cp = *(const float4*)&c_state[off];
        float cn[4], hn[4];
        const float cpv[4] = {cp.x, cp.y, cp.z, cp.w};
#pragma unroll
        for (int q = 0; q < 4; ++q) {
            const float ig = sigmoidf_(acc[0][j][q] + bi);
            const float fg = sigmoidf_(acc[1][j][q] + bf);
            const float gg = tanhf_  (acc[2][j][q] + bg);
            const float og = sigmoidf_(acc[3][j][q] + bo);
            const float cnv = fg * cpv[q] + ig * gg;
            cn[q] = cnv;
            hn[q] = og * tanhf_(cnv);
        }
        *(float4*)&c_state[off] = make_float4(cn[0], cn[1], cn[2], cn[3]);
        *(float4*)&h_out[off]   = make_float4(hn[0], hn[1], hn[2], hn[3]);
    }
}

extern "C" void kernel_launch(void* const* d_in, const int* in_sizes, int n_in,
                              void* d_out, int out_size, void* d_ws, size_t ws_size,
                              hipStream_t stream) {
    const float* x     = (const float*)d_in[0];  // [T, B, CX, 64, 64]
    const float* w_x2h = (const float*)d_in[1];
    const float* b_x2h = (const float*)d_in[2];
    const float* w_h2h = (const float*)d_in[3];
    const float* b_h2h = (const float*)d_in[4];
    float* out = (float*)d_out;                  // [T, B, HID, 64, 64]
    float* c_state = (float*)d_ws;               // [B, HID, 64, 64] fp32 (4 MB)

    const size_t x_step = (size_t)BATCH * CX * HW * HW;
    const size_t h_step = (size_t)BATCH * HID * HW * HW;

    dim3 grid(HW / TILE_H, HID, BATCH);   // (4, 64, 4) = 1024 blocks
    dim3 block(16, 8);                    // 128 threads = 2 waves

    for (int t = 0; t < TSTEPS; ++t) {
        const float* x_t    = x + (size_t)t * x_step;
        const float* h_prev = (t == 0) ? x : out + (size_t)(t - 1) * h_step;
        float* h_out        = out + (size_t)t * h_step;
        convlstm_step<<<grid, block, 0, stream>>>(
            x_t, h_prev, w_x2h, b_x2h, w_h2h, b_h2h, c_state, h_out, t == 0 ? 1 : 0);
    }
}

// Round 4
// 1120.459 us; speedup vs baseline: 3.1756x; 3.1756x over previous
//
#include <hip/hip_runtime.h>

// ConvLSTM fused, MI355X (gfx950). T=16, B=4, C=32, H=W=64, HID=64.
// Round 4: MFMA path (bf16x3 split precision, 9-shifted-GEMM conv).
//   - weights pre-transposed to [tap][o][c] bf16 hi/lo (c-contiguous frags)
//   - x pre-transposed to [t*b][66][66][32] bf16 hi/lo (padded, c-contiguous)
//   - per step: wave computes 4 gates x 16 hid x 32 px via mfma_f32_16x16x32_bf16,
//     K-loop = 9 taps x channel chunks; LSTM update register-local in epilogue;
//     writes h fp32 (d_out) + h bf16 hi/lo transposed (for next step's B).
// Fallback to the verified round-3 fp32 kernel if ws_size is too small.

#define TSTEPS 16
#define BATCH  4
#define CX     32
#define HID    64
#define HW     64
#define PW     66

typedef short bf16x8 __attribute__((ext_vector_type(8)));
typedef float f32x4  __attribute__((ext_vector_type(4)));
typedef unsigned short u16x4 __attribute__((ext_vector_type(4)));

__device__ __forceinline__ float sigmoidf_(float x){ return 1.0f/(1.0f+__expf(-x)); }
__device__ __forceinline__ float tanhf_(float x){ return 1.0f - 2.0f/(__expf(2.0f*x)+1.0f); }

__device__ __forceinline__ unsigned short f2bf(float f){
  unsigned u = __float_as_uint(f);
  return (unsigned short)((u + 0x7FFFu + ((u>>16)&1u)) >> 16);
}
__device__ __forceinline__ float bf2f(unsigned short s){ return __uint_as_float(((unsigned)s)<<16); }

// ---------------- prep kernels (once per call) ----------------

__global__ __launch_bounds__(256) void prep_w(
    const float* __restrict__ wx, const float* __restrict__ wh,
    unsigned short* __restrict__ wxh, unsigned short* __restrict__ wxl,
    unsigned short* __restrict__ whh, unsigned short* __restrict__ whl)
{
  int idx = blockIdx.x*256 + threadIdx.x;
  if (idx < 9*256*HID){
    int tap = idx / (256*HID);
    int rem = idx - tap*(256*HID);
    int o = rem >> 6, c = rem & 63;
    float v = wh[(o*HID + c)*9 + tap];
    unsigned short h = f2bf(v);
    whh[idx] = h;
    whl[idx] = f2bf(v - bf2f(h));
  }
  if (idx < 9*256*CX){
    int tap = idx / (256*CX);
    int rem = idx - tap*(256*CX);
    int o = rem >> 5, c = rem & 31;
    float v = wx[(o*CX + c)*9 + tap];
    unsigned short h = f2bf(v);
    wxh[idx] = h;
    wxl[idx] = f2bf(v - bf2f(h));
  }
}

// x [T*B, CX, 64, 64] fp32 -> xT [T*B, 66, 66, 32] bf16 hi/lo (pads zero)
__global__ __launch_bounds__(256) void prep_x(
    const float* __restrict__ x,
    unsigned short* __restrict__ xh, unsigned short* __restrict__ xl)
{
  __shared__ float tile[CX][HW];
  const int tb = blockIdx.x, yp = blockIdx.y, tid = threadIdx.x;
  const int y = yp - 1;
  const bool rowok = (y >= 0 && y < HW);
  if (rowok){
    const float* src = x + (size_t)tb*CX*HW*HW + y*HW;
    for (int i = tid; i < CX*HW; i += 256){
      int c = i >> 6, xc = i & 63;
      tile[c][xc] = src[(size_t)c*HW*HW + xc];
    }
  }
  __syncthreads();
  size_t base = ((size_t)tb*PW + yp)*PW*CX;
  for (int i = tid; i < PW*CX; i += 256){
    int xp = i >> 5, c = i & 31;
    int xg = xp - 1;
    float v = (rowok && xg >= 0 && xg < HW) ? tile[c][xg] : 0.f;
    unsigned short h = f2bf(v);
    xh[base+i] = h;
    xl[base+i] = f2bf(v - bf2f(h));
  }
}

__global__ __launch_bounds__(256) void zero_ws(unsigned long long* p, size_t n64){
  size_t i = (size_t)blockIdx.x*256 + threadIdx.x;
  size_t stride = (size_t)gridDim.x*256;
  for (; i < n64; i += stride) p[i] = 0ull;
}

// ---------------- the MFMA step kernel ----------------
// grid: (8 = chunk*2 + xhalf, 64 = y, 4 = b), block = 64 (one wave)
// wave: M = 4 gates x 16 hid (chunk), N = 32 x-positions (xhalf)

__global__ __launch_bounds__(64) void step_mfma(
    const unsigned short* __restrict__ xTh, const unsigned short* __restrict__ xTl,
    const unsigned short* __restrict__ wxh, const unsigned short* __restrict__ wxl,
    const unsigned short* __restrict__ whh, const unsigned short* __restrict__ whl,
    const unsigned short* __restrict__ hph, const unsigned short* __restrict__ hpl,
    unsigned short* __restrict__ hch, unsigned short* __restrict__ hcl,
    const float* __restrict__ bxb, const float* __restrict__ bhb,
    float* __restrict__ c_state,   // [B][64y][64x][64hid] fp32
    float* __restrict__ h_out,     // [B][HID][64][64] fp32 (d_out slice t)
    int t, int first)
{
  const int lane = threadIdx.x;
  const int nn = lane & 15, q = lane >> 4;
  const int chunk = blockIdx.x >> 1, xh_ = blockIdx.x & 1;
  const int y = blockIdx.y, b = blockIdx.z;
  const int m0 = chunk * 16;

  f32x4 acc[4][2];
#pragma unroll
  for (int g = 0; g < 4; ++g)
#pragma unroll
    for (int ns = 0; ns < 2; ++ns)
      acc[g][ns] = (f32x4){0.f, 0.f, 0.f, 0.f};

  const int tb = t*BATCH + b;

  for (int tap = 0; tap < 9; ++tap){
    const int ky = tap / 3;
    const int kx = tap - ky*3;
    const int yy = y + ky;            // padded row index (y + dy + 1)

    // ---- x2h: K = 32 (one chunk) ----
    {
      const size_t aoff = ((size_t)(tap*256 + m0 + nn))*CX + q*8;
      bf16x8 ah[4], al[4];
#pragma unroll
      for (int g = 0; g < 4; ++g){
        ah[g] = *(const bf16x8*)(wxh + aoff + (size_t)g*HID*CX);
        al[g] = *(const bf16x8*)(wxl + aoff + (size_t)g*HID*CX);
      }
#pragma unroll
      for (int ns = 0; ns < 2; ++ns){
        const size_t boff = (((size_t)tb*PW + yy)*PW + (xh_*32 + ns*16 + kx + nn))*CX + q*8;
        bf16x8 bh = *(const bf16x8*)(xTh + boff);
        bf16x8 bl = *(const bf16x8*)(xTl + boff);
#pragma unroll
        for (int g = 0; g < 4; ++g){
          acc[g][ns] = __builtin_amdgcn_mfma_f32_16x16x32_bf16(ah[g], bh, acc[g][ns], 0, 0, 0);
          acc[g][ns] = __builtin_amdgcn_mfma_f32_16x16x32_bf16(ah[g], bl, acc[g][ns], 0, 0, 0);
          acc[g][ns] = __builtin_amdgcn_mfma_f32_16x16x32_bf16(al[g], bh, acc[g][ns], 0, 0, 0);
        }
      }
    }

    // ---- h2h: K = 64 (two chunks) ----
    if (!first){
#pragma unroll
      for (int kc = 0; kc < 2; ++kc){
        const size_t aoff = ((size_t)(tap*256 + m0 + nn))*HID + kc*32 + q*8;
        bf16x8 ah[4], al[4];
#pragma unroll
        for (int g = 0; g < 4; ++g){
          ah[g] = *(const bf16x8*)(whh + aoff + (size_t)g*HID*HID);
          al[g] = *(const bf16x8*)(whl + aoff + (size_t)g*HID*HID);
        }
#pragma unroll
        for (int ns = 0; ns < 2; ++ns){
          const size_t boff = (((size_t)b*PW + yy)*PW + (xh_*32 + ns*16 + kx + nn))*HID + kc*32 + q*8;
          bf16x8 bh = *(const bf16x8*)(hph + boff);
          bf16x8 bl = *(const bf16x8*)(hpl + boff);
#pragma unroll
          for (int g = 0; g < 4; ++g){
            acc[g][ns] = __builtin_amdgcn_mfma_f32_16x16x32_bf16(ah[g], bh, acc[g][ns], 0, 0, 0);
            acc[g][ns] = __builtin_amdgcn_mfma_f32_16x16x32_bf16(ah[g], bl, acc[g][ns], 0, 0, 0);
            acc[g][ns] = __builtin_amdgcn_mfma_f32_16x16x32_bf16(al[g], bh, acc[g][ns], 0, 0, 0);
          }
        }
      }
    }
  }

  // ---- epilogue: LSTM update, register-local ----
  // D layout: col = lane&15 = n (x), row = q*4 + r (hid within chunk)
  f32x4 bxv[4], bhv[4];
#pragma unroll
  for (int g = 0; g < 4; ++g){
    bxv[g] = *(const f32x4*)&bxb[g*HID + m0 + 4*q];
    bhv[g] = *(const f32x4*)&bhb[g*HID + m0 + 4*q];
  }
#pragma unroll
  for (int ns = 0; ns < 2; ++ns){
    const int xg = xh_*32 + ns*16 + nn;
    const size_t coff = (((size_t)b*HW + y)*HW + xg)*HID + m0 + 4*q;
    f32x4 cp = (f32x4){0.f, 0.f, 0.f, 0.f};
    if (!first) cp = *(const f32x4*)&c_state[coff];
    f32x4 cn;
    float hn[4];
#pragma unroll
    for (int r = 0; r < 4; ++r){
      float iv = sigmoidf_(acc[0][ns][r] + bxv[0][r] + bhv[0][r]);
      float fv = sigmoidf_(acc[1][ns][r] + bxv[1][r] + bhv[1][r]);
      float gv = tanhf_  (acc[2][ns][r] + bxv[2][r] + bhv[2][r]);
      float ov = sigmoidf_(acc[3][ns][r] + bxv[3][r] + bhv[3][r]);
      float cnv = fv*cp[r] + iv*gv;
      cn[r] = cnv;
      hn[r] = ov * tanhf_(cnv);
    }
    *(f32x4*)&c_state[coff] = cn;
#pragma unroll
    for (int r = 0; r < 4; ++r)
      h_out[(((size_t)b*HID + m0 + 4*q + r)*HW + y)*HW + xg] = hn[r];
    const size_t hoff = (((size_t)b*PW + (y+1))*PW + (xg+1))*HID + m0 + 4*q;
    u16x4 ph, pl;
#pragma unroll
    for (int r = 0; r < 4; ++r){
      unsigned short h = f2bf(hn[r]);
      ph[r] = h;
      pl[r] = f2bf(hn[r] - bf2f(h));
    }
    *(u16x4*)&hch[hoff] = ph;
    *(u16x4*)&hcl[hoff] = pl;
  }
}

// ---------------- fallback: round-3 fp32 kernel (verified) ----------------

#define FCHUNK  8
#define FTILE_H 16
#define FROWS   (FTILE_H + 2)
#define FSTRIDE 68

__device__ __forceinline__ void do_chunk_f(
    float tile[FCHUNK][FROWS][FSTRIDE],
    const float* __restrict__ src,
    const float* __restrict__ wp0, const float* __restrict__ wp1,
    const float* __restrict__ wp2, const float* __restrict__ wp3,
    int gy0, int txg, int ty, int tid, float (&acc)[4][2][4])
{
  __syncthreads();
  for (int s = tid; s < FCHUNK * FROWS * 32; s += 128) {
    int c2 = s & 31;
    int rowid = s >> 5;
    int ic = rowid / FROWS;
    int r  = rowid - ic * FROWS;
    int gy = gy0 - 1 + r;
    if ((unsigned)gy < (unsigned)HW) {
      float2 v = *(const float2*)&src[(ic << 12) + (gy << 6) + (c2 << 1)];
      *(float2*)&tile[ic][r][2 + (c2 << 1)] = v;
    }
  }
  __syncthreads();
  for (int ic = 0; ic < FCHUNK; ++ic) {
    float w0[9], w1[9], w2[9], w3[9];
#pragma unroll
    for (int k = 0; k < 9; ++k) {
      w0[k] = wp0[ic*9+k]; w1[k] = wp1[ic*9+k];
      w2[k] = wp2[ic*9+k]; w3[k] = wp3[ic*9+k];
    }
    float rv[4][8];
#pragma unroll
    for (int rr = 0; rr < 4; ++rr) {
      const float* p = &tile[ic][2*ty+rr][4*txg];
      float4 a  = *(const float4*)p;
      float4 bb = *(const float4*)(p + 4);
      rv[rr][0]=a.x; rv[rr][1]=a.y; rv[rr][2]=a.z; rv[rr][3]=a.w;
      rv[rr][4]=bb.x; rv[rr][5]=bb.y; rv[rr][6]=bb.z; rv[rr][7]=bb.w;
    }
#pragma unroll
    for (int j = 0; j < 2; ++j)
#pragma unroll
      for (int dy = 0; dy < 3; ++dy)
#pragma unroll
        for (int qq = 0; qq < 4; ++qq)
#pragma unroll
          for (int dx = 0; dx < 3; ++dx) {
            float v = rv[j+dy][qq+dx+1];
            int k = dy*3+dx;
            acc[0][j][qq] = fmaf(v, w0[k], acc[0][j][qq]);
            acc[1][j][qq] = fmaf(v, w1[k], acc[1][j][qq]);
            acc[2][j][qq] = fmaf(v, w2[k], acc[2][j][qq]);
            acc[3][j][qq] = fmaf(v, w3[k], acc[3][j][qq]);
          }
  }
}

__global__ __launch_bounds__(128) void convlstm_step_f(
    const float* __restrict__ x_t, const float* __restrict__ h_prev,
    const float* __restrict__ w_x2h, const float* __restrict__ b_x2h,
    const float* __restrict__ w_h2h, const float* __restrict__ b_h2h,
    float* __restrict__ c_state, float* __restrict__ h_out, int first)
{
  __shared__ float tile[FCHUNK][FROWS][FSTRIDE];
  const int txg = threadIdx.x, ty = threadIdx.y;
  const int tid = ty*16 + txg;
  const int by = blockIdx.x, hc = blockIdx.y, b = blockIdx.z;
  const int gy0 = by * FTILE_H;
  {
    float2* p = (float2*)&tile[0][0][0];
    for (int i = tid; i < FCHUNK*FROWS*FSTRIDE/2; i += 128)
      p[i] = make_float2(0.f, 0.f);
  }
  float acc[4][2][4];
#pragma unroll
  for (int g = 0; g < 4; ++g)
#pragma unroll
    for (int j = 0; j < 2; ++j)
#pragma unroll
      for (int qq = 0; qq < 4; ++qq) acc[g][j][qq] = 0.f;
  {
    const float* wx0 = w_x2h + (size_t)(0*HID+hc)*CX*9;
    const float* wx1 = w_x2h + (size_t)(1*HID+hc)*CX*9;
    const float* wx2 = w_x2h + (size_t)(2*HID+hc)*CX*9;
    const float* wx3 = w_x2h + (size_t)(3*HID+hc)*CX*9;
    for (int c0 = 0; c0 < CX; c0 += FCHUNK)
      do_chunk_f(tile, x_t + ((size_t)(b*CX+c0) << 12),
                 wx0+c0*9, wx1+c0*9, wx2+c0*9, wx3+c0*9, gy0, txg, ty, tid, acc);
  }
  if (!first){
    const float* wh0 = w_h2h + (size_t)(0*HID+hc)*HID*9;
    const float* wh1 = w_h2h + (size_t)(1*HID+hc)*HID*9;
    const float* wh2 = w_h2h + (size_t)(2*HID+hc)*HID*9;
    const float* wh3 = w_h2h + (size_t)(3*HID+hc)*HID*9;
    for (int c0 = 0; c0 < HID; c0 += FCHUNK)
      do_chunk_f(tile, h_prev + ((size_t)(b*HID+c0) << 12),
                 wh0+c0*9, wh1+c0*9, wh2+c0*9, wh3+c0*9, gy0, txg, ty, tid, acc);
  }
  const float bi = b_x2h[0*HID+hc] + b_h2h[0*HID+hc];
  const float bf = b_x2h[1*HID+hc] + b_h2h[1*HID+hc];
  const float bg = b_x2h[2*HID+hc] + b_h2h[2*HID+hc];
  const float bo = b_x2h[3*HID+hc] + b_h2h[3*HID+hc];
#pragma unroll
  for (int j = 0; j < 2; ++j){
    const int row = gy0 + 2*ty + j;
    const int off = ((b*HID + hc)*HW + row)*HW + 4*txg;
    float4 cp = make_float4(0.f,0.f,0.f,0.f);
    if (!first) cp = *(const float4*)&c_state[off];
    float cn[4], hn[4];
    const float cpv[4] = {cp.x, cp.y, cp.z, cp.w};
#pragma unroll
    for (int qq = 0; qq < 4; ++qq){
      const float ig = sigmoidf_(acc[0][j][qq] + bi);
      const float fg = sigmoidf_(acc[1][j][qq] + bf);
      const float gg = tanhf_  (acc[2][j][qq] + bg);
      const float og = sigmoidf_(acc[3][j][qq] + bo);
      const float cnv = fg*cpv[qq] + ig*gg;
      cn[qq] = cnv;
      hn[qq] = og * tanhf_(cnv);
    }
    *(float4*)&c_state[off] = make_float4(cn[0],cn[1],cn[2],cn[3]);
    *(float4*)&h_out[off]   = make_float4(hn[0],hn[1],hn[2],hn[3]);
  }
}

// ---------------- launcher ----------------

extern "C" void kernel_launch(void* const* d_in, const int* in_sizes, int n_in,
                              void* d_out, int out_size, void* d_ws, size_t ws_size,
                              hipStream_t stream) {
  const float* x     = (const float*)d_in[0];
  const float* w_x2h = (const float*)d_in[1];
  const float* b_x2h = (const float*)d_in[2];
  const float* w_h2h = (const float*)d_in[3];
  const float* b_h2h = (const float*)d_in[4];
  float* out = (float*)d_out;

  // ws layout (256-aligned)
  size_t off = 0;
  auto alloc = [&](size_t bytes) -> char* {
    char* p = (char*)d_ws + off;
    off += (bytes + 255) & ~(size_t)255;
    return p;
  };
  float* c_state = (float*)alloc((size_t)BATCH*HW*HW*HID*4);          // 4 MB
  unsigned short* wxT_hi = (unsigned short*)alloc(9*256*CX*2);
  unsigned short* wxT_lo = (unsigned short*)alloc(9*256*CX*2);
  unsigned short* whT_hi = (unsigned short*)alloc(9*256*HID*2);
  unsigned short* whT_lo = (unsigned short*)alloc(9*256*HID*2);
  const size_t hT_bytes = (size_t)BATCH*PW*PW*HID*2;                  // 2,230,272
  unsigned short* hA_hi = (unsigned short*)alloc(hT_bytes);
  unsigned short* hA_lo = (unsigned short*)alloc(hT_bytes);
  unsigned short* hB_hi = (unsigned short*)alloc(hT_bytes);
  unsigned short* hB_lo = (unsigned short*)alloc(hT_bytes);
  const size_t xT_bytes = (size_t)TSTEPS*BATCH*PW*PW*CX*2;            // 17,842,176
  unsigned short* xT_hi = (unsigned short*)alloc(xT_bytes);
  unsigned short* xT_lo = (unsigned short*)alloc(xT_bytes);
  const size_t need = off;

  const size_t x_step = (size_t)BATCH*CX*HW*HW;
  const size_t h_step = (size_t)BATCH*HID*HW*HW;

  if (need <= ws_size) {
    // ---- MFMA path ----
    prep_w<<<(9*256*HID + 255)/256, 256, 0, stream>>>(
        w_x2h, w_h2h, wxT_hi, wxT_lo, whT_hi, whT_lo);
    prep_x<<<dim3(TSTEPS*BATCH, PW), 256, 0, stream>>>(x, xT_hi, xT_lo);
    // zero the 4 contiguous hT buffers
    zero_ws<<<1024, 256, 0, stream>>>((unsigned long long*)hA_hi, 4*hT_bytes/8);

    for (int t = 0; t < TSTEPS; ++t) {
      unsigned short* hp_hi = (t & 1) ? hA_hi : hB_hi;
      unsigned short* hp_lo = (t & 1) ? hA_lo : hB_lo;
      unsigned short* hc_hi = (t & 1) ? hB_hi : hA_hi;
      unsigned short* hc_lo = (t & 1) ? hB_lo : hA_lo;
      step_mfma<<<dim3(8, HW, BATCH), 64, 0, stream>>>(
          xT_hi, xT_lo, wxT_hi, wxT_lo, whT_hi, whT_lo,
          hp_hi, hp_lo, hc_hi, hc_lo,
          b_x2h, b_h2h, c_state, out + (size_t)t*h_step, t, t == 0 ? 1 : 0);
    }
  } else {
    // ---- fallback fp32 path (round 3) ----
    dim3 grid(HW / FTILE_H, HID, BATCH);
    dim3 block(16, 8);
    for (int t = 0; t < TSTEPS; ++t) {
      const float* x_t    = x + (size_t)t*x_step;
      const float* h_prev = (t == 0) ? x : out + (size_t)(t-1)*h_step;
      float* h_out        = out + (size_t)t*h_step;
      convlstm_step_f<<<grid, block, 0, stream>>>(
          x_t, h_prev, w_x2h, b_x2h, w_h2h, b_h2h, c_state, h_out, t == 0 ? 1 : 0);
    }
  }
}